// Round 4
// baseline (1762.994 us; speedup 1.0000x reference)
//
#include <hip/hip_runtime.h>
#include <hip/hip_bf16.h>
#include <math.h>

#define NS 100000
#define NR 100000
#define NE 600000
#define SILU_NORM 1.679177f

typedef __attribute__((ext_vector_type(8))) short short8;
typedef __attribute__((ext_vector_type(4))) float f32x4;

static __device__ __forceinline__ short f2bf(float f) {
    return __builtin_bit_cast(short, __float2bfloat16(f));
}

// ---------------------------------------------------------------------------
// Pre-swizzle a weight matrix W[K][128] (f32, k = u*8+v) into frag-major bf16:
// flat = s*4096 + f*512 + quad*128 + wl*8 + j  <-  W[(s*32+quad*8+j)*128 + w]
// w = f*16+wl (standard) or wl*8+f (colperm: used for fc2 so that MFMA output
// position (f,wl) holds physical channel wl*8+f -> lane-contiguous epilogue).
// ---------------------------------------------------------------------------
__global__ void swz_kernel(const float* __restrict__ W,
                           __hip_bfloat16* __restrict__ out, int total,
                           int colperm)
{
    int idx = blockIdx.x * 256 + threadIdx.x;
    if (idx >= total) return;
    int s = idx >> 12, r = idx & 4095;
    int f = r >> 9;  r &= 511;
    int quad = r >> 7; r &= 127;
    int wl = r >> 3;
    int j = r & 7;
    int k = s * 32 + quad * 8 + j;
    int w = colperm ? (wl * 8 + f) : (f * 16 + wl);
    out[idx] = __float2bfloat16(W[(size_t)k * 128 + w]);
}

// ---------------------------------------------------------------------------
// Counting sort of edges by dst: hist -> scan (3-pass) -> scatter.
// Scatter also emits dst/src/eattr in sorted order (contiguous loads later).
// Buffers live in d_out (free until the final kernel overwrites it).
// ---------------------------------------------------------------------------
__global__ __launch_bounds__(256) void hist_kernel(const int* __restrict__ edst,
                                                   int* __restrict__ cnt)
{
    int i = blockIdx.x * 256 + threadIdx.x;
    if (i < NE) atomicAdd(&cnt[edst[i]], 1);
}

#define SCAN_BLK 1024   // elements per scan block (256 thr x 4)

__global__ __launch_bounds__(256) void scan1_kernel(const int* __restrict__ cnt,
                                                    int* __restrict__ bsum, int n)
{
    __shared__ int ts[256];
    int b = blockIdx.x, t = threadIdx.x;
    int base = b * SCAN_BLK + t * 4;
    int s = 0;
    #pragma unroll
    for (int k = 0; k < 4; ++k) { int i = base + k; if (i < n) s += cnt[i]; }
    ts[t] = s; __syncthreads();
    #pragma unroll
    for (int off = 128; off; off >>= 1) {
        if (t < off) ts[t] += ts[t + off];
        __syncthreads();
    }
    if (t == 0) bsum[b] = ts[0];
}

__global__ __launch_bounds__(128) void scan2_kernel(const int* __restrict__ bsum,
                                                    int* __restrict__ bofs, int nb)
{
    __shared__ int sh[128];
    int t = threadIdx.x;
    sh[t] = (t < nb) ? bsum[t] : 0;
    __syncthreads();
    for (int off = 1; off < 128; off <<= 1) {
        int v = (t >= off) ? sh[t - off] : 0;
        __syncthreads();
        sh[t] += v;
        __syncthreads();
    }
    if (t < nb) bofs[t] = (t == 0) ? 0 : sh[t - 1];
}

__global__ __launch_bounds__(256) void scan3_kernel(const int* __restrict__ cnt,
                                                    const int* __restrict__ bofs,
                                                    int* __restrict__ ofs, int n)
{
    __shared__ int ts[256];
    int b = blockIdx.x, t = threadIdx.x;
    int base = b * SCAN_BLK + t * 4;
    int v[4]; int s = 0;
    #pragma unroll
    for (int k = 0; k < 4; ++k) {
        int i = base + k;
        v[k] = (i < n) ? cnt[i] : 0;
        s += v[k];
    }
    ts[t] = s; __syncthreads();
    for (int off = 1; off < 256; off <<= 1) {
        int u = (t >= off) ? ts[t - off] : 0;
        __syncthreads();
        ts[t] += u;
        __syncthreads();
    }
    int run = bofs[b] + ts[t] - s;   // exclusive across threads
    #pragma unroll
    for (int k = 0; k < 4; ++k) {
        int i = base + k;
        if (i < n) ofs[i] = run;
        run += v[k];
    }
}

__global__ __launch_bounds__(256) void scatter_kernel(
    const int* __restrict__ edst, const int* __restrict__ esrc,
    const float* __restrict__ eattr, int* __restrict__ ofs,
    int* __restrict__ perm, int* __restrict__ edst_s,
    int* __restrict__ esrc_s, float* __restrict__ eattr_s)
{
    int i = blockIdx.x * 256 + threadIdx.x;
    if (i < NE) {
        int d = edst[i];
        int pos = atomicAdd(&ofs[d], 1);
        perm[pos] = i;
        edst_s[pos] = d;
        esrc_s[pos] = esrc[i];
        eattr_s[pos] = eattr[i];
    }
}

// ---------------------------------------------------------------------------
// fctp via MFMA, register-resident: NO LDS, NO barriers. Each lane holds its
// row's 32 needed x values (cols quad+4j) in VGPRs; B-frags read direct from
// the swizzled weight table (same addresses across all waves -> L1/L2 convoy).
// 64 nodes/block (4 waves x 16 rows), grid ~1563 -> fully co-resident.
// ---------------------------------------------------------------------------
__global__ __launch_bounds__(256) void fctp_reg_kernel(
    const float* __restrict__ x, const float* __restrict__ y,
    const __hip_bfloat16* __restrict__ Wswz, float* __restrict__ out,
    float scale, int N)
{
    const int tid = threadIdx.x;
    const int lane = tid & 63;
    const int wv = tid >> 6;
    const int quad = lane >> 4;
    const int wl = lane & 15;
    const int n0 = blockIdx.x * 64;

    int row = n0 + wv * 16 + wl;
    if (row >= N) row = N - 1;

    float ya[8];
    {
        const float4* yp = (const float4*)(y + (size_t)row * 8);
        float4 a = yp[0], b = yp[1];
        ya[0] = a.x; ya[1] = a.y; ya[2] = a.z; ya[3] = a.w;
        ya[4] = b.x; ya[5] = b.y; ya[6] = b.z; ya[7] = b.w;
    }

    // x[row][quad + 4j]: the only 32 values this lane ever needs
    float xr[32];
    #pragma unroll
    for (int j = 0; j < 32; ++j)
        xr[j] = x[(size_t)row * 128 + quad + 4 * j];

    f32x4 acc[8];
    #pragma unroll
    for (int f = 0; f < 8; ++f) acc[f] = (f32x4){0.f, 0.f, 0.f, 0.f};

    #pragma unroll 4
    for (int s = 0; s < 32; ++s) {          // s = k-step; u = s*4 + quad
        float xv = xr[s];
        short8 af;
        #pragma unroll
        for (int v = 0; v < 8; ++v) af[v] = f2bf(xv * ya[v]);
        #pragma unroll
        for (int f = 0; f < 8; ++f) {
            short8 bfr = *(const short8*)((const short*)Wswz +
                                          (size_t)s * 4096 + (f * 64 + lane) * 8);
            acc[f] = __builtin_amdgcn_mfma_f32_16x16x32_bf16(af, bfr, acc[f], 0, 0, 0);
        }
    }

    #pragma unroll
    for (int r = 0; r < 4; ++r) {
        int node = n0 + wv * 16 + quad * 4 + r;
        if (node < N) {
            #pragma unroll
            for (int f = 0; f < 8; ++f)
                out[(size_t)node * 128 + f * 16 + wl] = acc[f][r] * scale;
        }
    }
}

// ---------------------------------------------------------------------------
// Edge kernel over dst-SORTED edges. fc1 A direct from escal (via perm),
// fc1/fc2 B direct from swizzled weights; hA transpose in LDS (only barrier).
// fc2 B columns PERMUTED so lane wl owns channels wl*8..wl*8+7: sf gather is
// 2x dwordx4/edge, atomics are 8 consecutive dwords. Sorted-run merge flushes
// one atomic batch per distinct dst in each quad's 4-edge group.
// ---------------------------------------------------------------------------
__global__ __launch_bounds__(256, 4) void edge_mfma_kernel(
    const int* __restrict__ perm, const int* __restrict__ edst_s,
    const int* __restrict__ esrc_s, const float* __restrict__ eattr_s,
    const float* __restrict__ escal,
    const __hip_bfloat16* __restrict__ W1swz,   // 8192  shorts (K=64)
    const __hip_bfloat16* __restrict__ W2swz,   // 16384 shorts (K=128, colperm)
    const float* __restrict__ sf, float* __restrict__ rfeat)
{
    __shared__ __hip_bfloat16 hA[16384];   // 32 KB  A-frag-major hidden

    const int tid = threadIdx.x;
    const int lane = tid & 63;
    const int wv = tid >> 6;
    const int quad = lane >> 4;
    const int wl = lane & 15;
    const int e0 = blockIdx.x * 128;

    // permuted edge id for this lane's A-frag rows (row m = wl)
    int epm[2];
    #pragma unroll
    for (int mt = 0; mt < 2; ++mt) {
        int j = e0 + (wv * 2 + mt) * 16 + wl;
        if (j >= NE) j = NE - 1;
        epm[mt] = perm[j];
    }

    // epilogue metadata, hoisted: contiguous sorted loads per quad 4-group
    const float s128 = 0.08838834764831845f;   // 1/sqrt(128)
    int4 dstv[2], srcv[2];
    float4 eav[2];
    bool valid[2];
    #pragma unroll
    for (int mt = 0; mt < 2; ++mt) {
        int jb = e0 + (wv * 2 + mt) * 16 + quad * 4;
        valid[mt] = (jb < NE);      // NE%4==0 -> whole group valid when jb<NE
        int jc = valid[mt] ? jb : 0;
        dstv[mt] = *(const int4*)(edst_s + jc);
        srcv[mt] = *(const int4*)(esrc_s + jc);
        eav[mt]  = *(const float4*)(eattr_s + jc);
    }

    // ---- fc1: [128 x 64] @ [64 x 128] ----
    short8 af1[2][2];
    #pragma unroll
    for (int ks = 0; ks < 2; ++ks)
        #pragma unroll
        for (int mt = 0; mt < 2; ++mt) {
            const float4* p = (const float4*)(escal + (size_t)epm[mt] * 64 +
                                              ks * 32 + quad * 8);
            float4 a = p[0], b = p[1];
            short8 v;
            v[0] = f2bf(a.x); v[1] = f2bf(a.y); v[2] = f2bf(a.z); v[3] = f2bf(a.w);
            v[4] = f2bf(b.x); v[5] = f2bf(b.y); v[6] = f2bf(b.z); v[7] = f2bf(b.w);
            af1[ks][mt] = v;
        }

    f32x4 acc1[2][8];
    #pragma unroll
    for (int mt = 0; mt < 2; ++mt)
        #pragma unroll
        for (int f = 0; f < 8; ++f) acc1[mt][f] = (f32x4){0.f, 0.f, 0.f, 0.f};

    #pragma unroll
    for (int ks = 0; ks < 2; ++ks)
        #pragma unroll
        for (int f = 0; f < 8; ++f) {
            short8 bfr = *(const short8*)((const short*)W1swz +
                                          (size_t)ks * 4096 + (f * 64 + lane) * 8);
            acc1[0][f] = __builtin_amdgcn_mfma_f32_16x16x32_bf16(
                af1[ks][0], bfr, acc1[0][f], 0, 0, 0);
            acc1[1][f] = __builtin_amdgcn_mfma_f32_16x16x32_bf16(
                af1[ks][1], bfr, acc1[1][f], 0, 0, 0);
        }

    // silu + write h to hA in fc2 A-frag order
    #pragma unroll
    for (int mt = 0; mt < 2; ++mt) {
        int MT = wv * 2 + mt;
        #pragma unroll
        for (int f = 0; f < 8; ++f) {
            int s2 = f >> 1;
            int q2 = ((f & 1) * 2 + (wl >> 3)) & 3;
            int j2 = wl & 7;
            #pragma unroll
            for (int r = 0; r < 4; ++r) {
                float t = acc1[mt][f][r] * 0.125f;              // 1/sqrt(64)
                float h = SILU_NORM * t / (1.f + __expf(-t));
                int lpos = q2 * 16 + quad * 4 + r;
                ((short*)hA)[((size_t)(s2 * 8 + MT) * 64 + lpos) * 8 + j2] = f2bf(h);
            }
        }
    }
    __syncthreads();

    // ---- fc2: [128 x 128] @ [128 x 128], colperm B ----
    f32x4 acc2[2][8];
    #pragma unroll
    for (int mt = 0; mt < 2; ++mt)
        #pragma unroll
        for (int f = 0; f < 8; ++f) acc2[mt][f] = (f32x4){0.f, 0.f, 0.f, 0.f};

    #pragma unroll
    for (int ks = 0; ks < 4; ++ks) {
        short8 afA = *(const short8*)((const short*)hA +
                                      ((size_t)(ks * 8 + wv * 2 + 0) * 64 + lane) * 8);
        short8 afB = *(const short8*)((const short*)hA +
                                      ((size_t)(ks * 8 + wv * 2 + 1) * 64 + lane) * 8);
        #pragma unroll
        for (int f = 0; f < 8; ++f) {
            short8 bfr = *(const short8*)((const short*)W2swz +
                                          (size_t)ks * 4096 + (f * 64 + lane) * 8);
            acc2[0][f] = __builtin_amdgcn_mfma_f32_16x16x32_bf16(
                afA, bfr, acc2[0][f], 0, 0, 0);
            acc2[1][f] = __builtin_amdgcn_mfma_f32_16x16x32_bf16(
                afB, bfr, acc2[1][f], 0, 0, 0);
        }
    }

    // epilogue: lane wl owns channels c = wl*8 + (0..7) (colperm).
    // Sorted-run merge; one atomic batch per distinct dst in the 4-group.
    #pragma unroll
    for (int mt = 0; mt < 2; ++mt) {
        if (!valid[mt]) continue;
        int dsts[4] = {dstv[mt].x, dstv[mt].y, dstv[mt].z, dstv[mt].w};
        int srcs[4] = {srcv[mt].x, srcv[mt].y, srcv[mt].z, srcv[mt].w};
        float eas[4] = {eav[mt].x * s128, eav[mt].y * s128,
                        eav[mt].z * s128, eav[mt].w * s128};
        // prefetch all 4 sf row-slices (independent loads, overlap latency)
        float4 g0[4], g1[4];
        #pragma unroll
        for (int r = 0; r < 4; ++r) {
            const float4* gp = (const float4*)(sf + (size_t)srcs[r] * 128 + wl * 8);
            g0[r] = gp[0];
            g1[r] = gp[1];
        }
        float run[8];
        int curdst = dsts[0];
        #pragma unroll
        for (int j = 0; j < 8; ++j) {
            float g = (j < 4) ? ((const float*)&g0[0])[j] : ((const float*)&g1[0])[j - 4];
            run[j] = acc2[mt][j][0] * eas[0] * g;
        }
        #pragma unroll
        for (int r = 1; r < 4; ++r) {
            float val[8];
            #pragma unroll
            for (int j = 0; j < 8; ++j) {
                float g = (j < 4) ? ((const float*)&g0[r])[j] : ((const float*)&g1[r])[j - 4];
                val[j] = acc2[mt][j][r] * eas[r] * g;
            }
            if (dsts[r] == curdst) {
                #pragma unroll
                for (int j = 0; j < 8; ++j) run[j] += val[j];
            } else {
                #pragma unroll
                for (int j = 0; j < 8; ++j)
                    atomicAdd(&rfeat[(size_t)curdst * 128 + wl * 8 + j], run[j]);
                curdst = dsts[r];
                #pragma unroll
                for (int j = 0; j < 8; ++j) run[j] = val[j];
            }
        }
        #pragma unroll
        for (int j = 0; j < 8; ++j)
            atomicAdd(&rfeat[(size_t)curdst * 128 + wl * 8 + j], run[j]);
    }
}

// ---------------------------------------------------------------------------
// Fused tail, register-resident like fctp_reg: conv = fctp(rfeat, rattr,
// W_lin2); angle from the same f32 A-products; out = cos(a)*rsc + sin(a)*conv.
// NO LDS, NO barriers.
// ---------------------------------------------------------------------------
__global__ __launch_bounds__(256) void conv_fuse_kernel(
    const float* __restrict__ x, const float* __restrict__ y,
    const __hip_bfloat16* __restrict__ Wswz, const float* __restrict__ W3,
    const float* __restrict__ rsc, float* __restrict__ out, int N)
{
    const int tid = threadIdx.x;
    const int lane = tid & 63;
    const int wv = tid >> 6;
    const int quad = lane >> 4;
    const int wl = lane & 15;
    const int n0 = blockIdx.x * 64;

    int row = n0 + wv * 16 + wl;
    if (row >= N) row = N - 1;

    float ya[8];
    {
        const float4* yp = (const float4*)(y + (size_t)row * 8);
        float4 a = yp[0], b = yp[1];
        ya[0] = a.x; ya[1] = a.y; ya[2] = a.z; ya[3] = a.w;
        ya[4] = b.x; ya[5] = b.y; ya[6] = b.z; ya[7] = b.w;
    }

    float xr[32];
    #pragma unroll
    for (int j = 0; j < 32; ++j)
        xr[j] = x[(size_t)row * 128 + quad + 4 * j];

    f32x4 acc[8];
    #pragma unroll
    for (int f = 0; f < 8; ++f) acc[f] = (f32x4){0.f, 0.f, 0.f, 0.f};
    float aacc = 0.f;

    #pragma unroll 4
    for (int s = 0; s < 32; ++s) {          // u = s*4 + quad
        float xv = xr[s];
        const float4* wp = (const float4*)(W3 + (s * 4 + quad) * 8);
        float4 w3a = wp[0], w3b = wp[1];
        float w3v[8] = {w3a.x, w3a.y, w3a.z, w3a.w, w3b.x, w3b.y, w3b.z, w3b.w};
        short8 af;
        #pragma unroll
        for (int v = 0; v < 8; ++v) {
            float pr = xv * ya[v];
            af[v] = f2bf(pr);
            aacc += pr * w3v[v];
        }
        #pragma unroll
        for (int f = 0; f < 8; ++f) {
            short8 bfr = *(const short8*)((const short*)Wswz +
                                          (size_t)s * 4096 + (f * 64 + lane) * 8);
            acc[f] = __builtin_amdgcn_mfma_f32_16x16x32_bf16(af, bfr, acc[f], 0, 0, 0);
        }
    }

    // angle: reduce partials across the 4 quads holding the same row (wl)
    float a = aacc;
    a += __shfl_xor(a, 16);
    a += __shfl_xor(a, 32);
    float ared = a * 5.524271728019903e-4f;   // 0.1/(32*sqrt(32))

    const float cs = 5.524271728019903e-3f;   // 1/(32*sqrt(32))
    #pragma unroll
    for (int r = 0; r < 4; ++r) {
        int node = n0 + wv * 16 + quad * 4 + r;
        float an = __shfl(ared, quad * 4 + r);   // lane with wl == quad*4+r
        if (node < N) {
            float ca = __cosf(an), sa = __sinf(an);
            #pragma unroll
            for (int f = 0; f < 8; ++f) {
                size_t o = (size_t)node * 128 + f * 16 + wl;
                out[o] = ca * rsc[o] + sa * (acc[f][r] * cs);
            }
        }
    }
}

// ---------------------------------------------------------------------------
extern "C" void kernel_launch(void* const* d_in, const int* in_sizes, int n_in,
                              void* d_out, int out_size, void* d_ws, size_t ws_size,
                              hipStream_t stream)
{
    const float* sender_input   = (const float*)d_in[0];
    const float* sender_attr    = (const float*)d_in[1];
    const float* receiver_input = (const float*)d_in[2];
    const float* receiver_attr  = (const float*)d_in[3];
    const int*   edge_src  = (const int*)d_in[4];
    const int*   edge_dst  = (const int*)d_in[5];
    const float* edge_attr = (const float*)d_in[6];
    const float* edge_scal = (const float*)d_in[7];
    const float* W_sc   = (const float*)d_in[8];
    const float* W_lin1 = (const float*)d_in[9];
    const float* W_fc1  = (const float*)d_in[10];
    const float* W_fc2  = (const float*)d_in[11];
    const float* W_lin2 = (const float*)d_in[12];
    const float* W_lin3 = (const float*)d_in[13];

    char* ws = (char*)d_ws;
    float* sf    = (float*)(ws);               // 51.2 MB ; reused as rsc after edge kernel
    float* rfeat = (float*)(ws + 51200000);    // 51.2 MB
    __hip_bfloat16* Wl1s = (__hip_bfloat16*)(ws + 102400000);  // 262144 B
    __hip_bfloat16* Wscs = (__hip_bfloat16*)(ws + 102662144);  // 262144 B
    __hip_bfloat16* Wl2s = (__hip_bfloat16*)(ws + 102924288);  // 262144 B
    __hip_bfloat16* W1s  = (__hip_bfloat16*)(ws + 103186432);  // 16384 B
    __hip_bfloat16* W2s  = (__hip_bfloat16*)(ws + 103202816);  // 32768 B
    float* rsc = sf;

    // sort scratch lives in d_out (free until conv_fuse writes it)
    int*   perm    = (int*)d_out;                // NE
    int*   edst_s  = (int*)d_out + 600000;       // NE
    int*   esrc_s  = (int*)d_out + 1200000;      // NE
    float* eattr_s = (float*)d_out + 1800000;    // NE
    int*   cnt     = (int*)d_out + 2400000;      // NR
    int*   ofs     = (int*)d_out + 2500000;      // NR
    int*   bsum    = (int*)d_out + 2600000;      // <=128
    int*   bofs    = (int*)d_out + 2600128;

    // weight pre-swizzles (one-time per launch, tiny)
    swz_kernel<<<512, 256, 0, stream>>>(W_lin1, Wl1s, 131072, 0);
    swz_kernel<<<512, 256, 0, stream>>>(W_sc,   Wscs, 131072, 0);
    swz_kernel<<<512, 256, 0, stream>>>(W_lin2, Wl2s, 131072, 0);
    swz_kernel<<<32,  256, 0, stream>>>(W_fc1,  W1s,  8192,  0);
    swz_kernel<<<64,  256, 0, stream>>>(W_fc2,  W2s,  16384, 1);   // colperm

    hipMemsetAsync(rfeat, 0, (size_t)NR * 128 * 4, stream);
    hipMemsetAsync(cnt, 0, (size_t)NR * 4, stream);

    // counting sort of edges by dst (+ sorted metadata copies)
    const int nbScan = (NR + SCAN_BLK - 1) / SCAN_BLK;   // 98
    hist_kernel<<<(NE + 255) / 256, 256, 0, stream>>>(edge_dst, cnt);
    scan1_kernel<<<nbScan, 256, 0, stream>>>(cnt, bsum, NR);
    scan2_kernel<<<1, 128, 0, stream>>>(bsum, bofs, nbScan);
    scan3_kernel<<<nbScan, 256, 0, stream>>>(cnt, bofs, ofs, NR);
    scatter_kernel<<<(NE + 255) / 256, 256, 0, stream>>>(
        edge_dst, edge_src, edge_attr, ofs, perm, edst_s, esrc_s, eattr_s);

    // sender_features = fctp(sender_input, sender_attr, W_lin1), scale 1/32
    fctp_reg_kernel<<<(NS + 63) / 64, 256, 0, stream>>>(
        sender_input, sender_attr, Wl1s, sf, 0.03125f, NS);
    // edge FC + gather + sorted-merged scatter
    edge_mfma_kernel<<<(NE + 127) / 128, 256, 0, stream>>>(
        perm, edst_s, esrc_s, eattr_s, edge_scal, W1s, W2s, sf, rfeat);
    // rsc = fctp(receiver_input, rattr, W_sc) * 1/32  (overwrites sf slot)
    fctp_reg_kernel<<<(NR + 63) / 64, 256, 0, stream>>>(
        receiver_input, receiver_attr, Wscs, rsc, 0.03125f, NR);
    // fused conv + angle + trig combine -> out
    conv_fuse_kernel<<<(NR + 63) / 64, 256, 0, stream>>>(
        rfeat, receiver_attr, Wl2s, W_lin3, rsc, (float*)d_out, NR);
}

// Round 5
// 773.777 us; speedup vs baseline: 2.2784x; 2.2784x over previous
//
#include <hip/hip_runtime.h>
#include <hip/hip_bf16.h>
#include <math.h>

#define NS 100000
#define NR 100000
#define NE 600000
#define SILU_NORM 1.679177f

typedef __attribute__((ext_vector_type(8))) short short8;
typedef __attribute__((ext_vector_type(4))) float f32x4;

static __device__ __forceinline__ short f2bf(float f) {
    return __builtin_bit_cast(short, __float2bfloat16(f));
}

#define GLDS16(g, l)                                                         \
    __builtin_amdgcn_global_load_lds(                                        \
        (const __attribute__((address_space(1))) unsigned int*)(const void*)(g), \
        (__attribute__((address_space(3))) unsigned int*)(void*)(l), 16, 0, 0)

// ---------------------------------------------------------------------------
// Pre-swizzle a weight matrix W[K][128] (f32, k = u*8+v) into frag-major bf16:
// flat = s*4096 + f*512 + quad*128 + wl*8 + j  <-  W[(s*32+quad*8+j)*128 + f*16+wl]
// B-fragment = lane-contiguous 16B at (f*64+lane)*16B within kstep chunk s.
// ---------------------------------------------------------------------------
__global__ void swz_kernel(const float* __restrict__ W,
                           __hip_bfloat16* __restrict__ out, int total)
{
    int idx = blockIdx.x * 256 + threadIdx.x;
    if (idx >= total) return;
    int s = idx >> 12, r = idx & 4095;
    int f = r >> 9;  r &= 511;
    int quad = r >> 7; r &= 127;
    int wl = r >> 3;
    int j = r & 7;
    int k = s * 32 + quad * 8 + j;
    int w = f * 16 + wl;
    out[idx] = __float2bfloat16(W[(size_t)k * 128 + w]);
}

// ---------------------------------------------------------------------------
// Counting sort of edges by dst: hist -> scan -> scatter (+ sorted metadata
// copies so the edge epilogue does contiguous vector loads, not random 4B
// gathers: that was +115 MB of FETCH in R3). Scratch lives in d_out.
// ---------------------------------------------------------------------------
__global__ __launch_bounds__(256) void hist_kernel(const int* __restrict__ edst,
                                                   int* __restrict__ cnt)
{
    int i = blockIdx.x * 256 + threadIdx.x;
    if (i < NE) atomicAdd(&cnt[edst[i]], 1);
}

#define SCAN_BLK 1024   // elements per scan block (256 thr x 4)

__global__ __launch_bounds__(256) void scan1_kernel(const int* __restrict__ cnt,
                                                    int* __restrict__ bsum, int n)
{
    __shared__ int ts[256];
    int b = blockIdx.x, t = threadIdx.x;
    int base = b * SCAN_BLK + t * 4;
    int s = 0;
    #pragma unroll
    for (int k = 0; k < 4; ++k) { int i = base + k; if (i < n) s += cnt[i]; }
    ts[t] = s; __syncthreads();
    #pragma unroll
    for (int off = 128; off; off >>= 1) {
        if (t < off) ts[t] += ts[t + off];
        __syncthreads();
    }
    if (t == 0) bsum[b] = ts[0];
}

__global__ __launch_bounds__(128) void scan2_kernel(const int* __restrict__ bsum,
                                                    int* __restrict__ bofs, int nb)
{
    __shared__ int sh[128];
    int t = threadIdx.x;
    sh[t] = (t < nb) ? bsum[t] : 0;
    __syncthreads();
    for (int off = 1; off < 128; off <<= 1) {
        int v = (t >= off) ? sh[t - off] : 0;
        __syncthreads();
        sh[t] += v;
        __syncthreads();
    }
    if (t < nb) bofs[t] = (t == 0) ? 0 : sh[t - 1];
}

__global__ __launch_bounds__(256) void scan3_kernel(const int* __restrict__ cnt,
                                                    const int* __restrict__ bofs,
                                                    int* __restrict__ ofs, int n)
{
    __shared__ int ts[256];
    int b = blockIdx.x, t = threadIdx.x;
    int base = b * SCAN_BLK + t * 4;
    int v[4]; int s = 0;
    #pragma unroll
    for (int k = 0; k < 4; ++k) {
        int i = base + k;
        v[k] = (i < n) ? cnt[i] : 0;
        s += v[k];
    }
    ts[t] = s; __syncthreads();
    for (int off = 1; off < 256; off <<= 1) {
        int u = (t >= off) ? ts[t - off] : 0;
        __syncthreads();
        ts[t] += u;
        __syncthreads();
    }
    int run = bofs[b] + ts[t] - s;   // exclusive across threads
    #pragma unroll
    for (int k = 0; k < 4; ++k) {
        int i = base + k;
        if (i < n) ofs[i] = run;
        run += v[k];
    }
}

__global__ __launch_bounds__(256) void scatter_kernel(
    const int* __restrict__ edst, const int* __restrict__ esrc,
    const float* __restrict__ eattr, int* __restrict__ ofs,
    int* __restrict__ perm, int* __restrict__ edst_s,
    int* __restrict__ esrc_s, float* __restrict__ eattr_s)
{
    int i = blockIdx.x * 256 + threadIdx.x;
    if (i < NE) {
        int d = edst[i];
        int pos = atomicAdd(&ofs[d], 1);
        perm[pos] = i;
        edst_s[pos] = d;
        esrc_s[pos] = esrc[i];
        eattr_s[pos] = eattr[i];
    }
}

// ---------------------------------------------------------------------------
// fctp via MFMA, 2-phase double-buffered K-loop (LDS-staged; R3-proven).
// ---------------------------------------------------------------------------
__global__ __launch_bounds__(256) void fctp_mfma_kernel(
    const float* __restrict__ x, const float* __restrict__ y,
    const __hip_bfloat16* __restrict__ Wswz, float* __restrict__ out,
    float scale, int N)
{
    __shared__ __hip_bfloat16 Wb[2][8192];  // 32 KB
    __shared__ float xs[2][128 * 8];        // 8 KB

    const int tid = threadIdx.x;
    const int lane = tid & 63;
    const int wv = tid >> 6;
    const int quad = lane >> 4;
    const int wl = lane & 15;
    const int n0 = blockIdx.x * 128;

    float ya[2][8];
    #pragma unroll
    for (int mt = 0; mt < 2; ++mt) {
        int node = n0 + wv * 32 + mt * 16 + wl;
        if (node >= N) node = N - 1;
        const float4* yp = (const float4*)(y + (size_t)node * 8);
        float4 a = yp[0], b = yp[1];
        ya[mt][0] = a.x; ya[mt][1] = a.y; ya[mt][2] = a.z; ya[mt][3] = a.w;
        ya[mt][4] = b.x; ya[mt][5] = b.y; ya[mt][6] = b.z; ya[mt][7] = b.w;
    }

    f32x4 acc[2][8];
    #pragma unroll
    for (int mt = 0; mt < 2; ++mt)
        #pragma unroll
        for (int f = 0; f < 8; ++f)
            acc[mt][f] = (f32x4){0.f, 0.f, 0.f, 0.f};

    auto stage = [&](int b, int cc) {
        const char* src = (const char*)(Wswz + (size_t)cc * 8192);
        #pragma unroll
        for (int i = 0; i < 4; ++i) {
            int off = (i * 256 + tid) * 16;
            GLDS16(src + off, (char*)Wb[b] + off);
        }
        int nl = tid >> 1, c4 = (tid & 1) * 4;
        int node = n0 + nl;
        if (node >= N) node = N - 1;
        GLDS16(x + (size_t)node * 128 + cc * 8 + c4, (char*)xs[b] + tid * 16);
    };

    stage(0, 0);
    __syncthreads();

    for (int cc = 0; cc < 16; ++cc) {
        int cur = cc & 1;
        if (cc < 15) stage(cur ^ 1, cc + 1);

        #pragma unroll
        for (int ks = 0; ks < 2; ++ks) {
            short8 bfr[8];
            #pragma unroll
            for (int f = 0; f < 8; ++f)
                bfr[f] = *(const short8*)((const short*)Wb[cur] +
                                          (size_t)ks * 4096 + (f * 64 + lane) * 8);
            #pragma unroll
            for (int mt = 0; mt < 2; ++mt) {
                float xv = xs[cur][(wv * 32 + mt * 16 + wl) * 8 + ks * 4 + quad];
                short8 af;
                #pragma unroll
                for (int v = 0; v < 8; ++v) af[v] = f2bf(xv * ya[mt][v]);
                #pragma unroll
                for (int f = 0; f < 8; ++f)
                    acc[mt][f] = __builtin_amdgcn_mfma_f32_16x16x32_bf16(
                        af, bfr[f], acc[mt][f], 0, 0, 0);
            }
        }
        __syncthreads();
    }

    #pragma unroll
    for (int mt = 0; mt < 2; ++mt) {
        #pragma unroll
        for (int r = 0; r < 4; ++r) {
            int node = n0 + wv * 32 + mt * 16 + quad * 4 + r;
            if (node < N) {
                #pragma unroll
                for (int f = 0; f < 8; ++f)
                    out[(size_t)node * 128 + f * 16 + wl] = acc[f != f ? 0 : mt][f][r] * scale;
            }
        }
    }
}

// ---------------------------------------------------------------------------
// Edge kernel over dst-SORTED edges. R3 compute structure (fc1 A direct from
// escal via perm, B direct from swizzled weights, hA transpose in LDS) +
// sorted contiguous metadata + STANDARD f*16+wl epilogue layout (each atomic
// instruction's 16 wl-lanes = one contiguous 64B segment -> no write amp).
// ---------------------------------------------------------------------------
__global__ __launch_bounds__(256, 4) void edge_mfma_kernel(
    const int* __restrict__ perm, const int* __restrict__ edst_s,
    const int* __restrict__ esrc_s, const float* __restrict__ eattr_s,
    const float* __restrict__ escal,
    const __hip_bfloat16* __restrict__ W1swz,   // 8192  shorts (K=64)
    const __hip_bfloat16* __restrict__ W2swz,   // 16384 shorts (K=128)
    const float* __restrict__ sf, float* __restrict__ rfeat)
{
    __shared__ __hip_bfloat16 hA[16384];   // 32 KB  A-frag-major hidden

    const int tid = threadIdx.x;
    const int lane = tid & 63;
    const int wv = tid >> 6;
    const int quad = lane >> 4;
    const int wl = lane & 15;
    const int e0 = blockIdx.x * 128;

    // permuted edge id for this lane's A-frag rows (row m = wl)
    int epm[2];
    #pragma unroll
    for (int mt = 0; mt < 2; ++mt) {
        int j = e0 + (wv * 2 + mt) * 16 + wl;
        if (j >= NE) j = NE - 1;
        epm[mt] = perm[j];
    }

    // epilogue metadata, hoisted: contiguous sorted loads per quad 4-group
    const float s128 = 0.08838834764831845f;   // 1/sqrt(128)
    int4 dstv[2], srcv[2];
    float4 eav[2];
    bool valid[2];
    #pragma unroll
    for (int mt = 0; mt < 2; ++mt) {
        int jb = e0 + (wv * 2 + mt) * 16 + quad * 4;
        valid[mt] = (jb < NE);      // NE%4==0 -> whole group valid when jb<NE
        int jc = valid[mt] ? jb : 0;
        dstv[mt] = *(const int4*)(edst_s + jc);
        srcv[mt] = *(const int4*)(esrc_s + jc);
        eav[mt]  = *(const float4*)(eattr_s + jc);
    }

    // ---- fc1: [128 x 64] @ [64 x 128] ----
    short8 af1[2][2];
    #pragma unroll
    for (int ks = 0; ks < 2; ++ks)
        #pragma unroll
        for (int mt = 0; mt < 2; ++mt) {
            const float4* p = (const float4*)(escal + (size_t)epm[mt] * 64 +
                                              ks * 32 + quad * 8);
            float4 a = p[0], b = p[1];
            short8 v;
            v[0] = f2bf(a.x); v[1] = f2bf(a.y); v[2] = f2bf(a.z); v[3] = f2bf(a.w);
            v[4] = f2bf(b.x); v[5] = f2bf(b.y); v[6] = f2bf(b.z); v[7] = f2bf(b.w);
            af1[ks][mt] = v;
        }

    f32x4 acc1[2][8];
    #pragma unroll
    for (int mt = 0; mt < 2; ++mt)
        #pragma unroll
        for (int f = 0; f < 8; ++f) acc1[mt][f] = (f32x4){0.f, 0.f, 0.f, 0.f};

    #pragma unroll
    for (int ks = 0; ks < 2; ++ks)
        #pragma unroll
        for (int f = 0; f < 8; ++f) {
            short8 bfr = *(const short8*)((const short*)W1swz +
                                          (size_t)ks * 4096 + (f * 64 + lane) * 8);
            acc1[0][f] = __builtin_amdgcn_mfma_f32_16x16x32_bf16(
                af1[ks][0], bfr, acc1[0][f], 0, 0, 0);
            acc1[1][f] = __builtin_amdgcn_mfma_f32_16x16x32_bf16(
                af1[ks][1], bfr, acc1[1][f], 0, 0, 0);
        }

    // silu + write h to hA in fc2 A-frag order
    #pragma unroll
    for (int mt = 0; mt < 2; ++mt) {
        int MT = wv * 2 + mt;
        #pragma unroll
        for (int f = 0; f < 8; ++f) {
            int s2 = f >> 1;
            int q2 = ((f & 1) * 2 + (wl >> 3)) & 3;
            int j2 = wl & 7;
            #pragma unroll
            for (int r = 0; r < 4; ++r) {
                float t = acc1[mt][f][r] * 0.125f;              // 1/sqrt(64)
                float h = SILU_NORM * t / (1.f + __expf(-t));
                int lpos = q2 * 16 + quad * 4 + r;
                ((short*)hA)[((size_t)(s2 * 8 + MT) * 64 + lpos) * 8 + j2] = f2bf(h);
            }
        }
    }
    __syncthreads();

    // ---- fc2: [128 x 128] @ [128 x 128] ----
    f32x4 acc2[2][8];
    #pragma unroll
    for (int mt = 0; mt < 2; ++mt)
        #pragma unroll
        for (int f = 0; f < 8; ++f) acc2[mt][f] = (f32x4){0.f, 0.f, 0.f, 0.f};

    #pragma unroll
    for (int ks = 0; ks < 4; ++ks) {
        short8 afA = *(const short8*)((const short*)hA +
                                      ((size_t)(ks * 8 + wv * 2 + 0) * 64 + lane) * 8);
        short8 afB = *(const short8*)((const short*)hA +
                                      ((size_t)(ks * 8 + wv * 2 + 1) * 64 + lane) * 8);
        #pragma unroll
        for (int f = 0; f < 8; ++f) {
            short8 bfr = *(const short8*)((const short*)W2swz +
                                          (size_t)ks * 4096 + (f * 64 + lane) * 8);
            acc2[0][f] = __builtin_amdgcn_mfma_f32_16x16x32_bf16(
                afA, bfr, acc2[0][f], 0, 0, 0);
            acc2[1][f] = __builtin_amdgcn_mfma_f32_16x16x32_bf16(
                afB, bfr, acc2[1][f], 0, 0, 0);
        }
    }

    // epilogue: sorted-run merge; one atomic batch per distinct dst per
    // 4-edge group; channel layout f*16+wl (across-lane contiguous).
    #pragma unroll
    for (int mt = 0; mt < 2; ++mt) {
        if (!valid[mt]) continue;
        int dsts[4] = {dstv[mt].x, dstv[mt].y, dstv[mt].z, dstv[mt].w};
        int srcs[4] = {srcv[mt].x, srcv[mt].y, srcv[mt].z, srcv[mt].w};
        float eas[4] = {eav[mt].x * s128, eav[mt].y * s128,
                        eav[mt].z * s128, eav[mt].w * s128};
        // prefetch all 32 sf values (independent loads overlap latency)
        float g[4][8];
        #pragma unroll
        for (int r = 0; r < 4; ++r)
            #pragma unroll
            for (int f = 0; f < 8; ++f)
                g[r][f] = sf[(size_t)srcs[r] * 128 + f * 16 + wl];

        float run[8];
        int curdst = dsts[0];
        #pragma unroll
        for (int f = 0; f < 8; ++f)
            run[f] = acc2[mt][f][0] * eas[0] * g[0][f];
        #pragma unroll
        for (int r = 1; r < 4; ++r) {
            float val[8];
            #pragma unroll
            for (int f = 0; f < 8; ++f)
                val[f] = acc2[mt][f][r] * eas[r] * g[r][f];
            if (dsts[r] == curdst) {
                #pragma unroll
                for (int f = 0; f < 8; ++f) run[f] += val[f];
            } else {
                #pragma unroll
                for (int f = 0; f < 8; ++f)
                    atomicAdd(&rfeat[(size_t)curdst * 128 + f * 16 + wl], run[f]);
                curdst = dsts[r];
                #pragma unroll
                for (int f = 0; f < 8; ++f) run[f] = val[f];
            }
        }
        #pragma unroll
        for (int f = 0; f < 8; ++f)
            atomicAdd(&rfeat[(size_t)curdst * 128 + f * 16 + wl], run[f]);
    }
}

// ---------------------------------------------------------------------------
// Mega-fused receiver tail: in ONE kernel,
//   rsc  = fctp(receiver_input, rattr, W_sc)  * 1/32          (accA)
//   conv = fctp(rfeat,          rattr, W_lin2)* 1/(32*sqrt32) (accB)
//   ang  = 0.1/(32*sqrt32) * <A2, W3>  (VALU, alongside)
//   out  = cos(ang)*rsc + sin(ang)*conv
// Both weight tables staged per chunk (dbuf, 80KB LDS -> 2 blocks/CU);
// removes the rsc HBM round-trip (102 MB) and a whole kernel's staging.
// ---------------------------------------------------------------------------
__global__ __launch_bounds__(256) void recv_fuse_kernel(
    const float* __restrict__ xin,   // receiver_input
    const float* __restrict__ xrf,   // rfeat
    const float* __restrict__ y,     // receiver_attr
    const __hip_bfloat16* __restrict__ WscS,
    const __hip_bfloat16* __restrict__ Wl2S,
    const float* __restrict__ W3,
    float* __restrict__ out, int N)
{
    __shared__ __hip_bfloat16 WbA[2][8192];  // 32 KB  W_sc chunks
    __shared__ __hip_bfloat16 WbB[2][8192];  // 32 KB  W_lin2 chunks
    __shared__ float xsA[2][128 * 8];        // 8 KB   receiver_input chunk
    __shared__ float xsB[2][128 * 8];        // 8 KB   rfeat chunk

    const int tid = threadIdx.x;
    const int lane = tid & 63;
    const int wv = tid >> 6;
    const int quad = lane >> 4;
    const int wl = lane & 15;
    const int n0 = blockIdx.x * 128;

    float ya[2][8];
    #pragma unroll
    for (int mt = 0; mt < 2; ++mt) {
        int node = n0 + wv * 32 + mt * 16 + wl;
        if (node >= N) node = N - 1;
        const float4* yp = (const float4*)(y + (size_t)node * 8);
        float4 a = yp[0], b = yp[1];
        ya[mt][0] = a.x; ya[mt][1] = a.y; ya[mt][2] = a.z; ya[mt][3] = a.w;
        ya[mt][4] = b.x; ya[mt][5] = b.y; ya[mt][6] = b.z; ya[mt][7] = b.w;
    }

    f32x4 accA[2][8], accB[2][8];
    #pragma unroll
    for (int mt = 0; mt < 2; ++mt)
        #pragma unroll
        for (int f = 0; f < 8; ++f) {
            accA[mt][f] = (f32x4){0.f, 0.f, 0.f, 0.f};
            accB[mt][f] = (f32x4){0.f, 0.f, 0.f, 0.f};
        }
    float aacc[2] = {0.f, 0.f};

    auto stage = [&](int b, int cc) {
        const char* sA = (const char*)(WscS + (size_t)cc * 8192);
        const char* sB = (const char*)(Wl2S + (size_t)cc * 8192);
        #pragma unroll
        for (int i = 0; i < 4; ++i) {
            int off = (i * 256 + tid) * 16;
            GLDS16(sA + off, (char*)WbA[b] + off);
            GLDS16(sB + off, (char*)WbB[b] + off);
        }
        int nl = tid >> 1, c4 = (tid & 1) * 4;
        int node = n0 + nl;
        if (node >= N) node = N - 1;
        GLDS16(xin + (size_t)node * 128 + cc * 8 + c4, (char*)xsA[b] + tid * 16);
        GLDS16(xrf + (size_t)node * 128 + cc * 8 + c4, (char*)xsB[b] + tid * 16);
    };

    stage(0, 0);
    __syncthreads();

    for (int cc = 0; cc < 16; ++cc) {
        int cur = cc & 1;
        if (cc < 15) stage(cur ^ 1, cc + 1);

        #pragma unroll
        for (int ks = 0; ks < 2; ++ks) {
            // --- set A: receiver_input x W_sc ---
            {
                short8 bfr[8];
                #pragma unroll
                for (int f = 0; f < 8; ++f)
                    bfr[f] = *(const short8*)((const short*)WbA[cur] +
                                              (size_t)ks * 4096 + (f * 64 + lane) * 8);
                #pragma unroll
                for (int mt = 0; mt < 2; ++mt) {
                    float xv = xsA[cur][(wv * 32 + mt * 16 + wl) * 8 + ks * 4 + quad];
                    short8 af;
                    #pragma unroll
                    for (int v = 0; v < 8; ++v) af[v] = f2bf(xv * ya[mt][v]);
                    #pragma unroll
                    for (int f = 0; f < 8; ++f)
                        accA[mt][f] = __builtin_amdgcn_mfma_f32_16x16x32_bf16(
                            af, bfr[f], accA[mt][f], 0, 0, 0);
                }
            }
            // --- set B: rfeat x W_lin2 (+ angle dot with W3) ---
            {
                short8 bfr[8];
                #pragma unroll
                for (int f = 0; f < 8; ++f)
                    bfr[f] = *(const short8*)((const short*)WbB[cur] +
                                              (size_t)ks * 4096 + (f * 64 + lane) * 8);
                const float4* wp = (const float4*)(W3 + ((cc * 8 + ks * 4 + quad) * 8));
                float4 w3a = wp[0], w3b = wp[1];
                float w3v[8] = {w3a.x, w3a.y, w3a.z, w3a.w,
                                w3b.x, w3b.y, w3b.z, w3b.w};
                #pragma unroll
                for (int mt = 0; mt < 2; ++mt) {
                    float xv = xsB[cur][(wv * 32 + mt * 16 + wl) * 8 + ks * 4 + quad];
                    short8 af;
                    #pragma unroll
                    for (int v = 0; v < 8; ++v) {
                        float pr = xv * ya[mt][v];
                        af[v] = f2bf(pr);
                        aacc[mt] += pr * w3v[v];
                    }
                    #pragma unroll
                    for (int f = 0; f < 8; ++f)
                        accB[mt][f] = __builtin_amdgcn_mfma_f32_16x16x32_bf16(
                            af, bfr[f], accB[mt][f], 0, 0, 0);
                }
            }
        }
        __syncthreads();
    }

    // angle: reduce across the 4 quad-lanes sharing each node row (m = wl)
    float ared[2];
    #pragma unroll
    for (int mt = 0; mt < 2; ++mt) {
        float a = aacc[mt];
        a += __shfl_xor(a, 16);
        a += __shfl_xor(a, 32);
        ared[mt] = a * 5.524271728019903e-4f;   // 0.1/(32*sqrt(32))
    }

    const float csB = 5.524271728019903e-3f;    // 1/(32*sqrt(32))
    const float csA = 0.03125f;                 // 1/32
    #pragma unroll
    for (int mt = 0; mt < 2; ++mt) {
        #pragma unroll
        for (int r = 0; r < 4; ++r) {
            int node = n0 + wv * 32 + mt * 16 + quad * 4 + r;
            float an = __shfl(ared[mt], quad * 4 + r);   // lane with wl==quad*4+r
            if (node < N) {
                float ca = __cosf(an), sa = __sinf(an);
                #pragma unroll
                for (int f = 0; f < 8; ++f) {
                    size_t o = (size_t)node * 128 + f * 16 + wl;
                    out[o] = ca * (accA[mt][f][r] * csA) +
                             sa * (accB[mt][f][r] * csB);
                }
            }
        }
    }
}

// ---------------------------------------------------------------------------
extern "C" void kernel_launch(void* const* d_in, const int* in_sizes, int n_in,
                              void* d_out, int out_size, void* d_ws, size_t ws_size,
                              hipStream_t stream)
{
    const float* sender_input   = (const float*)d_in[0];
    const float* sender_attr    = (const float*)d_in[1];
    const float* receiver_input = (const float*)d_in[2];
    const float* receiver_attr  = (const float*)d_in[3];
    const int*   edge_src  = (const int*)d_in[4];
    const int*   edge_dst  = (const int*)d_in[5];
    const float* edge_attr = (const float*)d_in[6];
    const float* edge_scal = (const float*)d_in[7];
    const float* W_sc   = (const float*)d_in[8];
    const float* W_lin1 = (const float*)d_in[9];
    const float* W_fc1  = (const float*)d_in[10];
    const float* W_fc2  = (const float*)d_in[11];
    const float* W_lin2 = (const float*)d_in[12];
    const float* W_lin3 = (const float*)d_in[13];

    char* ws = (char*)d_ws;
    float* sf    = (float*)(ws);               // 51.2 MB
    float* rfeat = (float*)(ws + 51200000);    // 51.2 MB
    __hip_bfloat16* Wl1s = (__hip_bfloat16*)(ws + 102400000);  // 262144 B
    __hip_bfloat16* Wscs = (__hip_bfloat16*)(ws + 102662144);  // 262144 B
    __hip_bfloat16* Wl2s = (__hip_bfloat16*)(ws + 102924288);  // 262144 B
    __hip_bfloat16* W1s  = (__hip_bfloat16*)(ws + 103186432);  // 16384 B
    __hip_bfloat16* W2s  = (__hip_bfloat16*)(ws + 103202816);  // 32768 B

    // sort scratch lives in d_out (free until recv_fuse writes it)
    int*   perm    = (int*)d_out;                // NE
    int*   edst_s  = (int*)d_out + 600000;       // NE
    int*   esrc_s  = (int*)d_out + 1200000;      // NE
    float* eattr_s = (float*)d_out + 1800000;    // NE
    int*   cnt     = (int*)d_out + 2400000;      // NR
    int*   ofs     = (int*)d_out + 2500000;      // NR
    int*   bsum    = (int*)d_out + 2600000;      // <=128
    int*   bofs    = (int*)d_out + 2600128;

    // weight pre-swizzles (one-time per launch, tiny)
    swz_kernel<<<512, 256, 0, stream>>>(W_lin1, Wl1s, 131072);
    swz_kernel<<<512, 256, 0, stream>>>(W_sc,   Wscs, 131072);
    swz_kernel<<<512, 256, 0, stream>>>(W_lin2, Wl2s, 131072);
    swz_kernel<<<32,  256, 0, stream>>>(W_fc1,  W1s,  8192);
    swz_kernel<<<64,  256, 0, stream>>>(W_fc2,  W2s,  16384);

    hipMemsetAsync(rfeat, 0, (size_t)NR * 128 * 4, stream);
    hipMemsetAsync(cnt, 0, (size_t)NR * 4, stream);

    // counting sort of edges by dst (+ sorted metadata copies)
    const int nbScan = (NR + SCAN_BLK - 1) / SCAN_BLK;   // 98
    hist_kernel<<<(NE + 255) / 256, 256, 0, stream>>>(edge_dst, cnt);
    scan1_kernel<<<nbScan, 256, 0, stream>>>(cnt, bsum, NR);
    scan2_kernel<<<1, 128, 0, stream>>>(bsum, bofs, nbScan);
    scan3_kernel<<<nbScan, 256, 0, stream>>>(cnt, bofs, ofs, NR);
    scatter_kernel<<<(NE + 255) / 256, 256, 0, stream>>>(
        edge_dst, edge_src, edge_attr, ofs, perm, edst_s, esrc_s, eattr_s);

    // sender_features = fctp(sender_input, sender_attr, W_lin1), scale 1/32
    fctp_mfma_kernel<<<(NS + 127) / 128, 256, 0, stream>>>(
        sender_input, sender_attr, Wl1s, sf, 0.03125f, NS);
    // edge FC + gather + sorted-merged scatter
    edge_mfma_kernel<<<(NE + 127) / 128, 256, 0, stream>>>(
        perm, edst_s, esrc_s, eattr_s, edge_scal, W1s, W2s, sf, rfeat);
    // fused rsc + conv + angle + trig combine -> out
    recv_fuse_kernel<<<(NR + 127) / 128, 256, 0, stream>>>(
        receiver_input, rfeat, receiver_attr, Wscs, Wl2s, W_lin3,
        (float*)d_out, NR);
}

// Round 6
// 715.829 us; speedup vs baseline: 2.4629x; 1.0810x over previous
//
#include <hip/hip_runtime.h>
#include <hip/hip_bf16.h>
#include <math.h>

#define NS 100000
#define NR 100000
#define NE 600000
#define SILU_NORM 1.679177f

typedef __attribute__((ext_vector_type(8))) short short8;
typedef __attribute__((ext_vector_type(4))) float f32x4;

static __device__ __forceinline__ short f2bf(float f) {
    return __builtin_bit_cast(short, __float2bfloat16(f));
}

#define GLDS16(g, l)                                                         \
    __builtin_amdgcn_global_load_lds(                                        \
        (const __attribute__((address_space(1))) unsigned int*)(const void*)(g), \
        (__attribute__((address_space(3))) unsigned int*)(void*)(l), 16, 0, 0)

// ---------------------------------------------------------------------------
// Pre-swizzle a weight matrix W[K][128] (f32, k = u*8+v) into frag-major bf16:
// flat = s*4096 + f*512 + quad*128 + wl*8 + j  <-  W[(s*32+quad*8+j)*128 + f*16+wl]
// A B-fragment (or, identically laid out, an A-fragment of W^T) is a
// lane-contiguous 16B load at (f*64+lane)*16B within kstep chunk s.
// ---------------------------------------------------------------------------
__global__ void swz_kernel(const float* __restrict__ W,
                           __hip_bfloat16* __restrict__ out, int total)
{
    int idx = blockIdx.x * 256 + threadIdx.x;
    if (idx >= total) return;
    int s = idx >> 12, r = idx & 4095;
    int f = r >> 9;  r &= 511;
    int quad = r >> 7; r &= 127;
    int wl = r >> 3;
    int j = r & 7;
    int k = s * 32 + quad * 8 + j;
    int w = f * 16 + wl;
    out[idx] = __float2bfloat16(W[(size_t)k * 128 + w]);
}

// ---------------------------------------------------------------------------
// pi-permuted swizzle for W_fc2: k-slot (s,quad,j) holds hidden channel
// c = 32s + 16(j>>2) + 4*quad + (j&3). Chosen so that fc2's A-fragment slot
// (ks,quad,j) equals the value lane (quad,wl) already holds from the
// operand-swapped fc1 (channel f*16+quad*4+r with f=2ks+(j>>2), r=j&3):
// the fc1->fc2 transpose becomes a pure register relabeling. Zero LDS.
// ---------------------------------------------------------------------------
__global__ void swz2pi_kernel(const float* __restrict__ W,
                              __hip_bfloat16* __restrict__ out, int total)
{
    int idx = blockIdx.x * 256 + threadIdx.x;
    if (idx >= total) return;
    int s = idx >> 12, r = idx & 4095;
    int f = r >> 9;  r &= 511;
    int quad = r >> 7; r &= 127;
    int wl = r >> 3;
    int j = r & 7;
    int c = 32 * s + 16 * (j >> 2) + 4 * quad + (j & 3);   // pi(k-slot)
    int w = f * 16 + wl;
    out[idx] = __float2bfloat16(W[(size_t)c * 128 + w]);
}

// ---------------------------------------------------------------------------
// Counting sort of edges by dst: hist -> scan -> scatter (+ sorted metadata
// copies so the edge epilogue does contiguous vector loads). Scratch: d_out.
// ---------------------------------------------------------------------------
__global__ __launch_bounds__(256) void hist_kernel(const int* __restrict__ edst,
                                                   int* __restrict__ cnt)
{
    int i = blockIdx.x * 256 + threadIdx.x;
    if (i < NE) atomicAdd(&cnt[edst[i]], 1);
}

#define SCAN_BLK 1024   // elements per scan block (256 thr x 4)

__global__ __launch_bounds__(256) void scan1_kernel(const int* __restrict__ cnt,
                                                    int* __restrict__ bsum, int n)
{
    __shared__ int ts[256];
    int b = blockIdx.x, t = threadIdx.x;
    int base = b * SCAN_BLK + t * 4;
    int s = 0;
    #pragma unroll
    for (int k = 0; k < 4; ++k) { int i = base + k; if (i < n) s += cnt[i]; }
    ts[t] = s; __syncthreads();
    #pragma unroll
    for (int off = 128; off; off >>= 1) {
        if (t < off) ts[t] += ts[t + off];
        __syncthreads();
    }
    if (t == 0) bsum[b] = ts[0];
}

__global__ __launch_bounds__(128) void scan2_kernel(const int* __restrict__ bsum,
                                                    int* __restrict__ bofs, int nb)
{
    __shared__ int sh[128];
    int t = threadIdx.x;
    sh[t] = (t < nb) ? bsum[t] : 0;
    __syncthreads();
    for (int off = 1; off < 128; off <<= 1) {
        int v = (t >= off) ? sh[t - off] : 0;
        __syncthreads();
        sh[t] += v;
        __syncthreads();
    }
    if (t < nb) bofs[t] = (t == 0) ? 0 : sh[t - 1];
}

__global__ __launch_bounds__(256) void scan3_kernel(const int* __restrict__ cnt,
                                                    const int* __restrict__ bofs,
                                                    int* __restrict__ ofs, int n)
{
    __shared__ int ts[256];
    int b = blockIdx.x, t = threadIdx.x;
    int base = b * SCAN_BLK + t * 4;
    int v[4]; int s = 0;
    #pragma unroll
    for (int k = 0; k < 4; ++k) {
        int i = base + k;
        v[k] = (i < n) ? cnt[i] : 0;
        s += v[k];
    }
    ts[t] = s; __syncthreads();
    for (int off = 1; off < 256; off <<= 1) {
        int u = (t >= off) ? ts[t - off] : 0;
        __syncthreads();
        ts[t] += u;
        __syncthreads();
    }
    int run = bofs[b] + ts[t] - s;   // exclusive across threads
    #pragma unroll
    for (int k = 0; k < 4; ++k) {
        int i = base + k;
        if (i < n) ofs[i] = run;
        run += v[k];
    }
}

__global__ __launch_bounds__(256) void scatter_kernel(
    const int* __restrict__ edst, const int* __restrict__ esrc,
    const float* __restrict__ eattr, int* __restrict__ ofs,
    int* __restrict__ perm, int* __restrict__ edst_s,
    int* __restrict__ esrc_s, float* __restrict__ eattr_s)
{
    int i = blockIdx.x * 256 + threadIdx.x;
    if (i < NE) {
        int d = edst[i];
        int pos = atomicAdd(&ofs[d], 1);
        perm[pos] = i;
        edst_s[pos] = d;
        esrc_s[pos] = esrc[i];
        eattr_s[pos] = eattr[i];
    }
}

// ---------------------------------------------------------------------------
// fctp via MFMA, 2-phase double-buffered K-loop (R3-proven).
// ---------------------------------------------------------------------------
__global__ __launch_bounds__(256) void fctp_mfma_kernel(
    const float* __restrict__ x, const float* __restrict__ y,
    const __hip_bfloat16* __restrict__ Wswz, float* __restrict__ out,
    float scale, int N)
{
    __shared__ __hip_bfloat16 Wb[2][8192];  // 32 KB
    __shared__ float xs[2][128 * 8];        // 8 KB

    const int tid = threadIdx.x;
    const int lane = tid & 63;
    const int wv = tid >> 6;
    const int quad = lane >> 4;
    const int wl = lane & 15;
    const int n0 = blockIdx.x * 128;

    float ya[2][8];
    #pragma unroll
    for (int mt = 0; mt < 2; ++mt) {
        int node = n0 + wv * 32 + mt * 16 + wl;
        if (node >= N) node = N - 1;
        const float4* yp = (const float4*)(y + (size_t)node * 8);
        float4 a = yp[0], b = yp[1];
        ya[mt][0] = a.x; ya[mt][1] = a.y; ya[mt][2] = a.z; ya[mt][3] = a.w;
        ya[mt][4] = b.x; ya[mt][5] = b.y; ya[mt][6] = b.z; ya[mt][7] = b.w;
    }

    f32x4 acc[2][8];
    #pragma unroll
    for (int mt = 0; mt < 2; ++mt)
        #pragma unroll
        for (int f = 0; f < 8; ++f)
            acc[mt][f] = (f32x4){0.f, 0.f, 0.f, 0.f};

    auto stage = [&](int b, int cc) {
        const char* src = (const char*)(Wswz + (size_t)cc * 8192);
        #pragma unroll
        for (int i = 0; i < 4; ++i) {
            int off = (i * 256 + tid) * 16;
            GLDS16(src + off, (char*)Wb[b] + off);
        }
        int nl = tid >> 1, c4 = (tid & 1) * 4;
        int node = n0 + nl;
        if (node >= N) node = N - 1;
        GLDS16(x + (size_t)node * 128 + cc * 8 + c4, (char*)xs[b] + tid * 16);
    };

    stage(0, 0);
    __syncthreads();

    for (int cc = 0; cc < 16; ++cc) {
        int cur = cc & 1;
        if (cc < 15) stage(cur ^ 1, cc + 1);

        #pragma unroll
        for (int ks = 0; ks < 2; ++ks) {
            short8 bfr[8];
            #pragma unroll
            for (int f = 0; f < 8; ++f)
                bfr[f] = *(const short8*)((const short*)Wb[cur] +
                                          (size_t)ks * 4096 + (f * 64 + lane) * 8);
            #pragma unroll
            for (int mt = 0; mt < 2; ++mt) {
                float xv = xs[cur][(wv * 32 + mt * 16 + wl) * 8 + ks * 4 + quad];
                short8 af;
                #pragma unroll
                for (int v = 0; v < 8; ++v) af[v] = f2bf(xv * ya[mt][v]);
                #pragma unroll
                for (int f = 0; f < 8; ++f)
                    acc[mt][f] = __builtin_amdgcn_mfma_f32_16x16x32_bf16(
                        af, bfr[f], acc[mt][f], 0, 0, 0);
            }
        }
        __syncthreads();
    }

    #pragma unroll
    for (int mt = 0; mt < 2; ++mt) {
        #pragma unroll
        for (int r = 0; r < 4; ++r) {
            int node = n0 + wv * 32 + mt * 16 + quad * 4 + r;
            if (node < N) {
                #pragma unroll
                for (int f = 0; f < 8; ++f)
                    out[(size_t)node * 128 + f * 16 + wl] = acc[mt][f][r] * scale;
            }
        }
    }
}

// ---------------------------------------------------------------------------
// Edge kernel: ZERO LDS, ZERO barriers.
// fc1 operand-swapped: acc1 = mfma(A=W1-frag, B=es-frag) -> lane (q,wl) holds
// h[edge=wl][channel f*16+q*4+r]. fc2 uses pi-permuted W2 so its A-fragment
// slot (ks,j) is the lane's OWN register (f=2ks+(j>>2), r=j&3) after silu.
// Per-mt pipeline (fc1 -> pack -> fc2 -> epilogue) keeps VGPR bounded.
// Epilogue: sorted-run merge, one atomic batch per distinct dst per 4-group,
// channel layout f*16+wl (across-lane contiguous 64B atomic segments).
// ---------------------------------------------------------------------------
__global__ __launch_bounds__(256, 3) void edge_mfma_kernel(
    const int* __restrict__ perm, const int* __restrict__ edst_s,
    const int* __restrict__ esrc_s, const float* __restrict__ eattr_s,
    const float* __restrict__ escal,
    const __hip_bfloat16* __restrict__ W1swz,   // 8192  shorts (K=64, std swz)
    const __hip_bfloat16* __restrict__ W2swz,   // 16384 shorts (K=128, pi swz)
    const float* __restrict__ sf, float* __restrict__ rfeat)
{
    const int tid = threadIdx.x;
    const int lane = tid & 63;
    const int wv = tid >> 6;
    const int quad = lane >> 4;
    const int wl = lane & 15;
    const int e0 = blockIdx.x * 128;

    // permuted edge id for this lane's es-fragment rows (edge col = wl)
    int epm[2];
    #pragma unroll
    for (int mt = 0; mt < 2; ++mt) {
        int j = e0 + (wv * 2 + mt) * 16 + wl;
        if (j >= NE) j = NE - 1;
        epm[mt] = perm[j];
    }

    // epilogue metadata: contiguous sorted loads per quad 4-group
    const float s128 = 0.08838834764831845f;   // 1/sqrt(128)
    int4 dstv[2], srcv[2];
    float4 eav[2];
    bool valid[2];
    #pragma unroll
    for (int mt = 0; mt < 2; ++mt) {
        int jb = e0 + (wv * 2 + mt) * 16 + quad * 4;
        valid[mt] = (jb < NE);      // NE%4==0 -> whole group valid when jb<NE
        int jc = valid[mt] ? jb : 0;
        dstv[mt] = *(const int4*)(edst_s + jc);
        srcv[mt] = *(const int4*)(esrc_s + jc);
        eav[mt]  = *(const float4*)(eattr_s + jc);
    }

    // es B-fragments: lane holds es[edge=wl][ks*32 + quad*8 + 0..7]
    short8 af1[2][2];
    #pragma unroll
    for (int ks = 0; ks < 2; ++ks)
        #pragma unroll
        for (int mt = 0; mt < 2; ++mt) {
            const float4* p = (const float4*)(escal + (size_t)epm[mt] * 64 +
                                              ks * 32 + quad * 8);
            float4 a = p[0], b = p[1];
            short8 v;
            v[0] = f2bf(a.x); v[1] = f2bf(a.y); v[2] = f2bf(a.z); v[3] = f2bf(a.w);
            v[4] = f2bf(b.x); v[5] = f2bf(b.y); v[6] = f2bf(b.z); v[7] = f2bf(b.w);
            af1[ks][mt] = v;
        }

    #pragma unroll
    for (int mt = 0; mt < 2; ++mt) {
        // ---- fc1' = h^T: mfma(A=W1frag, B=esfrag) ----
        f32x4 acc1[8];
        #pragma unroll
        for (int f = 0; f < 8; ++f) acc1[f] = (f32x4){0.f, 0.f, 0.f, 0.f};
        #pragma unroll
        for (int ks = 0; ks < 2; ++ks)
            #pragma unroll
            for (int f = 0; f < 8; ++f) {
                short8 wf = *(const short8*)((const short*)W1swz +
                                             (size_t)ks * 4096 + (f * 64 + lane) * 8);
                acc1[f] = __builtin_amdgcn_mfma_f32_16x16x32_bf16(
                    wf, af1[ks][mt], acc1[f], 0, 0, 0);
            }

        // ---- silu + pack: fc2 A-frag slot (ks,j) = own reg (2ks+(j>>2), j&3)
        short8 af2[4];
        #pragma unroll
        for (int ks = 0; ks < 4; ++ks) {
            #pragma unroll
            for (int half = 0; half < 2; ++half) {
                int f = 2 * ks + half;
                #pragma unroll
                for (int r = 0; r < 4; ++r) {
                    float t = acc1[f][r] * 0.125f;              // 1/sqrt(64)
                    float h = SILU_NORM * t / (1.f + __expf(-t));
                    af2[ks][half * 4 + r] = f2bf(h);
                }
            }
        }

        // ---- fc2: [16 x 128] @ [128 x 128] (pi-permuted K) ----
        f32x4 acc2[8];
        #pragma unroll
        for (int f = 0; f < 8; ++f) acc2[f] = (f32x4){0.f, 0.f, 0.f, 0.f};
        #pragma unroll
        for (int ks = 0; ks < 4; ++ks)
            #pragma unroll
            for (int f = 0; f < 8; ++f) {
                short8 wf = *(const short8*)((const short*)W2swz +
                                             (size_t)ks * 4096 + (f * 64 + lane) * 8);
                acc2[f] = __builtin_amdgcn_mfma_f32_16x16x32_bf16(
                    af2[ks], wf, acc2[f], 0, 0, 0);
            }

        // ---- epilogue: sorted-run merge + atomics ----
        if (valid[mt]) {
            int dsts[4] = {dstv[mt].x, dstv[mt].y, dstv[mt].z, dstv[mt].w};
            int srcs[4] = {srcv[mt].x, srcv[mt].y, srcv[mt].z, srcv[mt].w};
            float eas[4] = {eav[mt].x * s128, eav[mt].y * s128,
                            eav[mt].z * s128, eav[mt].w * s128};
            float g[4][8];
            #pragma unroll
            for (int r = 0; r < 4; ++r)
                #pragma unroll
                for (int f = 0; f < 8; ++f)
                    g[r][f] = sf[(size_t)srcs[r] * 128 + f * 16 + wl];

            float run[8];
            int curdst = dsts[0];
            #pragma unroll
            for (int f = 0; f < 8; ++f)
                run[f] = acc2[f][0] * eas[0] * g[0][f];
            #pragma unroll
            for (int r = 1; r < 4; ++r) {
                float val[8];
                #pragma unroll
                for (int f = 0; f < 8; ++f)
                    val[f] = acc2[f][r] * eas[r] * g[r][f];
                if (dsts[r] == curdst) {
                    #pragma unroll
                    for (int f = 0; f < 8; ++f) run[f] += val[f];
                } else {
                    #pragma unroll
                    for (int f = 0; f < 8; ++f)
                        atomicAdd(&rfeat[(size_t)curdst * 128 + f * 16 + wl], run[f]);
                    curdst = dsts[r];
                    #pragma unroll
                    for (int f = 0; f < 8; ++f) run[f] = val[f];
                }
            }
            #pragma unroll
            for (int f = 0; f < 8; ++f)
                atomicAdd(&rfeat[(size_t)curdst * 128 + f * 16 + wl], run[f]);
        }
    }
}

// ---------------------------------------------------------------------------
// Fused tail: conv = fctp(rfeat, rattr, W_lin2), angle from the same f32
// A-products, out = cos(a)*rsc + sin(a)*conv. 2-phase dbuf K-loop (R3-proven).
// ---------------------------------------------------------------------------
__global__ __launch_bounds__(256) void conv_fuse_kernel(
    const float* __restrict__ x, const float* __restrict__ y,
    const __hip_bfloat16* __restrict__ Wswz, const float* __restrict__ W3,
    const float* __restrict__ rsc, float* __restrict__ out, int N)
{
    __shared__ __hip_bfloat16 Wb[2][8192];  // 32 KB
    __shared__ float xs[2][128 * 8];        // 8 KB

    const int tid = threadIdx.x;
    const int lane = tid & 63;
    const int wv = tid >> 6;
    const int quad = lane >> 4;
    const int wl = lane & 15;
    const int n0 = blockIdx.x * 128;

    float ya[2][8];
    #pragma unroll
    for (int mt = 0; mt < 2; ++mt) {
        int node = n0 + wv * 32 + mt * 16 + wl;
        if (node >= N) node = N - 1;
        const float4* yp = (const float4*)(y + (size_t)node * 8);
        float4 a = yp[0], b = yp[1];
        ya[mt][0] = a.x; ya[mt][1] = a.y; ya[mt][2] = a.z; ya[mt][3] = a.w;
        ya[mt][4] = b.x; ya[mt][5] = b.y; ya[mt][6] = b.z; ya[mt][7] = b.w;
    }

    f32x4 acc[2][8];
    #pragma unroll
    for (int mt = 0; mt < 2; ++mt)
        #pragma unroll
        for (int f = 0; f < 8; ++f)
            acc[mt][f] = (f32x4){0.f, 0.f, 0.f, 0.f};
    float aacc[2] = {0.f, 0.f};

    auto stage = [&](int b, int cc) {
        const char* src = (const char*)(Wswz + (size_t)cc * 8192);
        #pragma unroll
        for (int i = 0; i < 4; ++i) {
            int off = (i * 256 + tid) * 16;
            GLDS16(src + off, (char*)Wb[b] + off);
        }
        int nl = tid >> 1, c4 = (tid & 1) * 4;
        int node = n0 + nl;
        if (node >= N) node = N - 1;
        GLDS16(x + (size_t)node * 128 + cc * 8 + c4, (char*)xs[b] + tid * 16);
    };

    stage(0, 0);
    __syncthreads();

    for (int cc = 0; cc < 16; ++cc) {
        int cur = cc & 1;
        if (cc < 15) stage(cur ^ 1, cc + 1);

        #pragma unroll
        for (int ks = 0; ks < 2; ++ks) {
            short8 bfr[8];
            #pragma unroll
            for (int f = 0; f < 8; ++f)
                bfr[f] = *(const short8*)((const short*)Wb[cur] +
                                          (size_t)ks * 4096 + (f * 64 + lane) * 8);
            const float4* wp = (const float4*)(W3 + ((cc * 8 + ks * 4 + quad) * 8));
            float4 w3a = wp[0], w3b = wp[1];
            float w3v[8] = {w3a.x, w3a.y, w3a.z, w3a.w, w3b.x, w3b.y, w3b.z, w3b.w};
            #pragma unroll
            for (int mt = 0; mt < 2; ++mt) {
                float xv = xs[cur][(wv * 32 + mt * 16 + wl) * 8 + ks * 4 + quad];
                short8 af;
                #pragma unroll
                for (int v = 0; v < 8; ++v) {
                    float pr = xv * ya[mt][v];
                    af[v] = f2bf(pr);
                    aacc[mt] += pr * w3v[v];
                }
                #pragma unroll
                for (int f = 0; f < 8; ++f)
                    acc[mt][f] = __builtin_amdgcn_mfma_f32_16x16x32_bf16(
                        af, bfr[f], acc[mt][f], 0, 0, 0);
            }
        }
        __syncthreads();
    }

    float ared[2];
    #pragma unroll
    for (int mt = 0; mt < 2; ++mt) {
        float a = aacc[mt];
        a += __shfl_xor(a, 16);
        a += __shfl_xor(a, 32);
        ared[mt] = a * 5.524271728019903e-4f;   // 0.1/(32*sqrt(32))
    }

    const float cs = 5.524271728019903e-3f;     // 1/(32*sqrt(32))
    #pragma unroll
    for (int mt = 0; mt < 2; ++mt) {
        #pragma unroll
        for (int r = 0; r < 4; ++r) {
            int node = n0 + wv * 32 + mt * 16 + quad * 4 + r;
            float a = __shfl(ared[mt], quad * 4 + r);
            if (node < N) {
                float ca = __cosf(a), sa = __sinf(a);
                #pragma unroll
                for (int f = 0; f < 8; ++f) {
                    size_t o = (size_t)node * 128 + f * 16 + wl;
                    out[o] = ca * rsc[o] + sa * (acc[mt][f][r] * cs);
                }
            }
        }
    }
}

// ---------------------------------------------------------------------------
extern "C" void kernel_launch(void* const* d_in, const int* in_sizes, int n_in,
                              void* d_out, int out_size, void* d_ws, size_t ws_size,
                              hipStream_t stream)
{
    const float* sender_input   = (const float*)d_in[0];
    const float* sender_attr    = (const float*)d_in[1];
    const float* receiver_input = (const float*)d_in[2];
    const float* receiver_attr  = (const float*)d_in[3];
    const int*   edge_src  = (const int*)d_in[4];
    const int*   edge_dst  = (const int*)d_in[5];
    const float* edge_attr = (const float*)d_in[6];
    const float* edge_scal = (const float*)d_in[7];
    const float* W_sc   = (const float*)d_in[8];
    const float* W_lin1 = (const float*)d_in[9];
    const float* W_fc1  = (const float*)d_in[10];
    const float* W_fc2  = (const float*)d_in[11];
    const float* W_lin2 = (const float*)d_in[12];
    const float* W_lin3 = (const float*)d_in[13];

    char* ws = (char*)d_ws;
    float* sf    = (float*)(ws);               // 51.2 MB ; reused as rsc after edge kernel
    float* rfeat = (float*)(ws + 51200000);    // 51.2 MB
    __hip_bfloat16* Wl1s = (__hip_bfloat16*)(ws + 102400000);  // 262144 B
    __hip_bfloat16* Wscs = (__hip_bfloat16*)(ws + 102662144);  // 262144 B
    __hip_bfloat16* Wl2s = (__hip_bfloat16*)(ws + 102924288);  // 262144 B
    __hip_bfloat16* W1s  = (__hip_bfloat16*)(ws + 103186432);  // 16384 B
    __hip_bfloat16* W2s  = (__hip_bfloat16*)(ws + 103202816);  // 32768 B
    float* rsc = sf;

    // sort scratch lives in d_out (free until conv_fuse writes it)
    int*   perm    = (int*)d_out;                // NE
    int*   edst_s  = (int*)d_out + 600000;       // NE
    int*   esrc_s  = (int*)d_out + 1200000;      // NE
    float* eattr_s = (float*)d_out + 1800000;    // NE
    int*   cnt     = (int*)d_out + 2400000;      // NR
    int*   ofs     = (int*)d_out + 2500000;      // NR
    int*   bsum    = (int*)d_out + 2600000;      // <=128
    int*   bofs    = (int*)d_out + 2600128;

    // weight pre-swizzles (one-time per launch, tiny)
    swz_kernel<<<512, 256, 0, stream>>>(W_lin1, Wl1s, 131072);
    swz_kernel<<<512, 256, 0, stream>>>(W_sc,   Wscs, 131072);
    swz_kernel<<<512, 256, 0, stream>>>(W_lin2, Wl2s, 131072);
    swz_kernel<<<32,  256, 0, stream>>>(W_fc1,  W1s,  8192);
    swz2pi_kernel<<<64, 256, 0, stream>>>(W_fc2, W2s,  16384);   // pi-permuted

    hipMemsetAsync(rfeat, 0, (size_t)NR * 128 * 4, stream);
    hipMemsetAsync(cnt, 0, (size_t)NR * 4, stream);

    // counting sort of edges by dst (+ sorted metadata copies)
    const int nbScan = (NR + SCAN_BLK - 1) / SCAN_BLK;   // 98
    hist_kernel<<<(NE + 255) / 256, 256, 0, stream>>>(edge_dst, cnt);
    scan1_kernel<<<nbScan, 256, 0, stream>>>(cnt, bsum, NR);
    scan2_kernel<<<1, 128, 0, stream>>>(bsum, bofs, nbScan);
    scan3_kernel<<<nbScan, 256, 0, stream>>>(cnt, bofs, ofs, NR);
    scatter_kernel<<<(NE + 255) / 256, 256, 0, stream>>>(
        edge_dst, edge_src, edge_attr, ofs, perm, edst_s, esrc_s, eattr_s);

    // sender_features = fctp(sender_input, sender_attr, W_lin1), scale 1/32
    fctp_mfma_kernel<<<(NS + 127) / 128, 256, 0, stream>>>(
        sender_input, sender_attr, Wl1s, sf, 0.03125f, NS);
    // edge FC + gather + sorted-merged scatter (no-LDS pi version)
    edge_mfma_kernel<<<(NE + 127) / 128, 256, 0, stream>>>(
        perm, edst_s, esrc_s, eattr_s, edge_scal, W1s, W2s, sf, rfeat);
    // rsc = fctp(receiver_input, rattr, W_sc) * 1/32  (overwrites sf slot)
    fctp_mfma_kernel<<<(NR + 127) / 128, 256, 0, stream>>>(
        receiver_input, receiver_attr, Wscs, rsc, 0.03125f, NR);
    // fused conv + angle + trig combine -> out
    conv_fuse_kernel<<<(NR + 127) / 128, 256, 0, stream>>>(
        rfeat, receiver_attr, Wl2s, W_lin3, rsc, (float*)d_out, NR);
}